// Round 7
// baseline (256.145 us; speedup 1.0000x reference)
//
#include <hip/hip_runtime.h>
#include <cmath>

#define BB 32
#define SS 2048
#define IND 300
#define HID 16
#define LAT 16
#define NA 64
#define NITER 20
#define GRAV 0.01f

// d_out layout (floats): field[32*16] | rec[32*2048*300] | masses[32] | change[1]
#define OFF_FIELD 0
#define OFF_REC   512
#define OFF_MASS  (512 + BB*SS*IND)
#define OFF_CHG   (OFF_MASS + BB)

// d_ws layout (floats)
#define WS_FIELD 0      // 512 accumulators
#define WS_CHG   512    // 1 accumulator
// p[65536][16] staging lives in d_out's rec region (overwritten later by bcast)

typedef __attribute__((ext_vector_type(8))) __bf16 bf16x8;
typedef __attribute__((ext_vector_type(4))) __bf16 bf16x4;
typedef __attribute__((ext_vector_type(4))) float f32x4;

#define WTS 88   // W token-row stride (bf16) = 176 B: 16B-aligned, <=2-way banks

// ---------------------------------------------------------------------------
// Kernel 1: encoder only (split from gravity for attribution). 64 tokens per
// 256-thread block; split-K over 4 waves; p written in Bp-layout f32x4 so the
// gravity kernel reads it with zero conversion.
// ---------------------------------------------------------------------------
__global__ __launch_bounds__(256, 1)
void k_enc(const float* __restrict__ x, const float* __restrict__ w1,
           const float* __restrict__ b1, const float* __restrict__ w2,
           const float* __restrict__ b2, float* __restrict__ pbuf)
{
    __shared__ float hred[4][64][HID + 1];
    const int tid  = threadIdx.x;
    const int wave = tid >> 6, lane = tid & 63;
    const int quad = lane >> 4, col = lane & 15;
    const int tok0 = blockIdx.x * 64;

    // stage 1: partial h; chunks 76/76/76/72 (16B-aligned)
    {
        const int tl = tid & 63;
        const int ck = tid >> 6;
        const int base = ck * 76;
        const float* xrow = x + (size_t)(tok0 + tl) * IND + base;
        float h[HID];
        #pragma unroll
        for (int j = 0; j < HID; ++j) h[j] = 0.f;
        #pragma unroll 6
        for (int i = 0; i < 18; ++i) {
            f32x4 xv = *(const f32x4*)(xrow + i * 4);
            const float* wr = w1 + (base + i * 4) * HID;
            #pragma unroll
            for (int c = 0; c < 4; ++c)
                #pragma unroll
                for (int j = 0; j < HID; ++j)
                    h[j] = fmaf(xv[c], wr[c * HID + j], h[j]);
        }
        if (ck < 3) {
            f32x4 xv = *(const f32x4*)(xrow + 72);
            const float* wr = w1 + (base + 72) * HID;
            #pragma unroll
            for (int c = 0; c < 4; ++c)
                #pragma unroll
                for (int j = 0; j < HID; ++j)
                    h[j] = fmaf(xv[c], wr[c * HID + j], h[j]);
        }
        #pragma unroll
        for (int j = 0; j < HID; ++j) hred[ck][tl][j] = h[j];
    }
    __syncthreads();
    // stage 2: reduce chunks, +b1, relu
    {
        const int tl = tid & 63;
        const int jg = (tid >> 6) * 4;
        #pragma unroll
        for (int jj = 0; jj < 4; ++jj) {
            const int j = jg + jj;
            float s = (hred[0][tl][j] + hred[1][tl][j]) +
                      (hred[2][tl][j] + hred[3][tl][j]);
            hred[0][tl][j] = fmaxf(s + b1[j], 0.f);
        }
    }
    __syncthreads();
    // stage 3: p in Bp-layout: lane(quad,col) <- token wave*16+col, dims quad*4..+3
    {
        const float* hrow = &hred[0][wave * 16 + col][0];
        f32x4 acc = *(const f32x4*)(b2 + quad * 4);
        #pragma unroll
        for (int j = 0; j < HID; ++j) {
            float hj = hrow[j];
            f32x4 wv = *(const f32x4*)(w2 + j * LAT + quad * 4);
            #pragma unroll
            for (int r = 0; r < 4; ++r) acc[r] = fmaf(hj, wv[r], acc[r]);
        }
        ((f32x4*)pbuf)[(size_t)(tok0 + wave * 16 + col) * 4 + quad] = acc;
    }
}

// ---------------------------------------------------------------------------
// Kernel 2: gravity, transposed dataflow (R6 math), 2 MFMA tiles per wave for
// ILP (32 tokens/wave, 128/block, 512 blocks). Constants shared across tiles.
// ---------------------------------------------------------------------------
__global__ __launch_bounds__(256, 1)
void k_grav(const float* __restrict__ att, const float* __restrict__ pbuf,
            float* __restrict__ ws)
{
    __shared__ __bf16 Wl[4][2][16 * WTS];   // 22528 B
    const int tid  = threadIdx.x;
    const int wave = tid >> 6, lane = tid & 63;
    const int quad = lane >> 4, col = lane & 15;

    const f32x4 zf = {0.f, 0.f, 0.f, 0.f};
    bf16x8 ones8;
    #pragma unroll
    for (int e = 0; e < 8; ++e) ones8[e] = (__bf16)1.0f;

    // Aaug for S^T: A[m=16i+col][k]: k even -> -2*att[m][quad*4+k/2], odd -> 1
    bf16x8 aS[4];
    #pragma unroll
    for (int i = 0; i < 4; ++i) {
        f32x4 av = *(const f32x4*)(att + (16 * i + col) * LAT + quad * 4);
        #pragma unroll
        for (int m = 0; m < 4; ++m) {
            aS[i][2 * m]     = (__bf16)(-2.0f * av[m]);
            aS[i][2 * m + 1] = (__bf16)1.0f;
        }
    }
    // |a|^2 redistributed to C-layout positions
    f32x4 sanv[4];
    {
        float nrm[4];
        #pragma unroll
        for (int i = 0; i < 4; ++i) {
            const float* ar = att + (16 * i + col) * LAT;
            float s = 0.f;
            #pragma unroll
            for (int k = 0; k < LAT; ++k) s = fmaf(ar[k], ar[k], s);
            nrm[i] = s;
        }
        #pragma unroll
        for (int i = 0; i < 4; ++i)
            #pragma unroll
            for (int r = 0; r < 4; ++r)
                sanv[i][r] = __shfl(nrm[i], 16 * quad + quad * 4 + r);
    }
    // A2^T for F^T: A[m=d=col][k=a=32h+quad*8+j]
    bf16x8 aF[2];
    #pragma unroll
    for (int h = 0; h < 2; ++h)
        #pragma unroll
        for (int j = 0; j < 8; ++j)
            aF[h][j] = (__bf16)att[(32 * h + quad * 8 + j) * LAT + col];

    const int t0 = blockIdx.x * 128 + wave * 32 + col;
    f32x4 p[2];
    p[0] = ((const f32x4*)pbuf)[(size_t)t0 * 4 + quad];
    p[1] = ((const f32x4*)pbuf)[(size_t)(t0 + 16) * 4 + quad];

    __bf16* myW[2] = { &Wl[wave][0][0], &Wl[wave][1][0] };

    float cd = 0.f;
    #pragma unroll 1
    for (int it = 0; it < NITER; ++it) {
        bf16x8 bp[2];
        #pragma unroll
        for (int s = 0; s < 2; ++s)
            #pragma unroll
            for (int m = 0; m < 4; ++m) {
                float v = p[s][m];
                bp[s][2 * m]     = (__bf16)v;
                bp[s][2 * m + 1] = (__bf16)(v * v);
            }
        f32x4 sf[2][4];
        #pragma unroll
        for (int s = 0; s < 2; ++s)
            #pragma unroll
            for (int i = 0; i < 4; ++i)
                sf[s][i] = __builtin_amdgcn_mfma_f32_16x16x32_bf16(aS[i], bp[s], zf, 0, 0, 0);

        #pragma unroll
        for (int s = 0; s < 2; ++s)
            #pragma unroll
            for (int i = 0; i < 4; ++i) {
                bf16x4 wp;
                #pragma unroll
                for (int r = 0; r < 4; ++r)
                    wp[r] = (__bf16)__builtin_amdgcn_rcpf(sf[s][i][r] + sanv[i][r]);
                *(bf16x4*)(myW[s] + col * WTS + 16 * i + quad * 4) = wp;
            }
        bf16x8 bw[2][2];
        #pragma unroll
        for (int s = 0; s < 2; ++s)
            #pragma unroll
            for (int h = 0; h < 2; ++h)
                bw[s][h] = *(bf16x8*)(myW[s] + col * WTS + 32 * h + quad * 8);

        const bool last = (it == NITER - 1);
        #pragma unroll
        for (int s = 0; s < 2; ++s) {
            f32x4 F  = __builtin_amdgcn_mfma_f32_16x16x32_bf16(aF[0], bw[s][0], zf, 0, 0, 0);
            F  = __builtin_amdgcn_mfma_f32_16x16x32_bf16(aF[1], bw[s][1], F,  0, 0, 0);
            f32x4 F2 = __builtin_amdgcn_mfma_f32_16x16x32_bf16(ones8, bw[s][0], zf, 0, 0, 0);
            F2 = __builtin_amdgcn_mfma_f32_16x16x32_bf16(ones8, bw[s][1], F2, 0, 0, 0);
            #pragma unroll
            for (int r = 0; r < 4; ++r) {
                float np = fmaf(p[s][r], fmaf(F2[r], -0.1f * GRAV, 1.0f),
                                (0.1f * GRAV) * F[r]);
                if (last) { float d = np - p[s][r]; cd = fmaf(d, d, cd); }
                p[s][r] = np;
            }
        }
    }

    // field: sum both tiles, butterfly over the 16 col-lanes
    f32x4 fs;
    #pragma unroll
    for (int r = 0; r < 4; ++r) fs[r] = p[0][r] + p[1][r];
    #pragma unroll
    for (int m = 1; m <= 8; m <<= 1)
        #pragma unroll
        for (int r = 0; r < 4; ++r) fs[r] += __shfl_xor(fs[r], m);
    const int b = blockIdx.x >> 4;   // 16 blocks (128 tokens) per batch row
    if (col == 0) {
        #pragma unroll
        for (int r = 0; r < 4; ++r)
            atomicAdd(ws + WS_FIELD + b * LAT + quad * 4 + r, fs[r]);
    }
    float c2 = cd;
    c2 += __shfl_xor(c2, 1);  c2 += __shfl_xor(c2, 2);  c2 += __shfl_xor(c2, 4);
    c2 += __shfl_xor(c2, 8);  c2 += __shfl_xor(c2, 16); c2 += __shfl_xor(c2, 32);
    if (lane == 0) atomicAdd(ws + WS_CHG, c2);
}

// ---------------------------------------------------------------------------
// Kernel 3: fused finalize + broadcast. Each block recomputes the 300-float
// rec row for its batch (4.8k flop, trivial) then streams its 32 KB chunk.
// Blocks with c==0 also emit field/masses; block 0 emits change.
// ---------------------------------------------------------------------------
#define CHUNK 8192
#define CPB   (SS * IND / CHUNK)    // 75
__global__ __launch_bounds__(256)
void k_bcast(const float* __restrict__ dw1, const float* __restrict__ db1,
             const float* __restrict__ dw2, const float* __restrict__ db2,
             const float* __restrict__ mw,  const float* __restrict__ mb,
             const float* __restrict__ ws, float* __restrict__ out)
{
    __shared__ float sf[LAT];
    __shared__ float sh[HID];
    __shared__ __align__(16) float srow[IND];
    const int blk = blockIdx.x;
    const int b = blk / CPB, c = blk % CPB;
    const int t = threadIdx.x;

    if (t < LAT) {
        float f = ws[WS_FIELD + b * LAT + t] * (1.f / SS);
        sf[t] = f;
        if (c == 0) out[OFF_FIELD + b * LAT + t] = f;
    }
    __syncthreads();
    if (t < HID) {
        float a = db1[t];
        #pragma unroll
        for (int d = 0; d < LAT; ++d) a = fmaf(sf[d], dw1[d * HID + t], a);
        sh[t] = fmaxf(a, 0.f);
    }
    if (c == 0 && t == 32) {
        float a = mb[0];
        #pragma unroll
        for (int d = 0; d < LAT; ++d) a = fmaf(sf[d], mw[d], a);
        out[OFF_MASS + b] = 1.f / (1.f + expf(-a));
    }
    if (blk == 0 && t == 33) out[OFF_CHG] = sqrtf(ws[WS_CHG]);
    __syncthreads();
    {
        float a = db2[t % IND];   // t<300 path uses t; wrap harmless for t>=300
        if (t < IND) {
            a = db2[t];
            #pragma unroll
            for (int j = 0; j < HID; ++j) a = fmaf(sh[j], dw2[j * IND + t], a);
            srow[t] = a;
        }
        if (t < IND - 256) {
            const int tc = t + 256;
            float a2 = db2[tc];
            #pragma unroll
            for (int j = 0; j < HID; ++j) a2 = fmaf(sh[j], dw2[j * IND + tc], a2);
            srow[tc] = a2;
        }
    }
    __syncthreads();
    f32x4* o = (f32x4*)(out + OFF_REC + (size_t)b * (SS * IND) + (size_t)c * CHUNK);
    #pragma unroll
    for (int i = 0; i < CHUNK / 4 / 256; ++i) {
        const int o4 = i * 256 + t;
        const int r  = (c * CHUNK + o4 * 4) % IND;   // r % 4 == 0
        f32x4 v = *(const f32x4*)(srow + r);
        __builtin_nontemporal_store(v, o + o4);
    }
}

extern "C" void kernel_launch(void* const* d_in, const int* in_sizes, int n_in,
                              void* d_out, int out_size, void* d_ws, size_t ws_size,
                              hipStream_t stream)
{
    const float* x   = (const float*)d_in[0];
    const float* ew1 = (const float*)d_in[1];
    const float* eb1 = (const float*)d_in[2];
    const float* ew2 = (const float*)d_in[3];
    const float* eb2 = (const float*)d_in[4];
    const float* att = (const float*)d_in[5];
    const float* dw1 = (const float*)d_in[6];
    const float* db1 = (const float*)d_in[7];
    const float* dw2 = (const float*)d_in[8];
    const float* db2 = (const float*)d_in[9];
    const float* mw  = (const float*)d_in[10];
    const float* mb  = (const float*)d_in[11];
    float* out = (float*)d_out;
    float* ws  = (float*)d_ws;
    float* pbuf = out + OFF_REC;   // 4 MB p staging inside rec region (overwritten by k_bcast)

    (void)hipMemsetAsync(ws, 0, (WS_CHG + 1) * sizeof(float), stream);
    k_enc <<<BB * SS / 64, 256, 0, stream>>>(x, ew1, eb1, ew2, eb2, pbuf);
    k_grav<<<BB * SS / 128, 256, 0, stream>>>(att, pbuf, ws);
    k_bcast<<<BB * CPB, 256, 0, stream>>>(dw1, db1, dw2, db2, mw, mb, ws, out);
}

// Round 9
// 234.035 us; speedup vs baseline: 1.0945x; 1.0945x over previous
//
#include <hip/hip_runtime.h>
#include <cmath>

#define BB 32
#define SS 2048
#define IND 300
#define HID 16
#define LAT 16
#define NA 64
#define NITER 20
#define GRAV 0.01f

// d_out layout (floats): field[32*16] | rec[32*2048*300] | masses[32] | change[1]
#define OFF_FIELD 0
#define OFF_REC   512
#define OFF_MASS  (512 + BB*SS*IND)
#define OFF_CHG   (OFF_MASS + BB)

// d_ws layout (floats)
#define WS_FIELD 0      // 512 accumulators
#define WS_CHG   512    // 1 accumulator

typedef __attribute__((ext_vector_type(8))) __bf16 bf16x8;
typedef __attribute__((ext_vector_type(4))) __bf16 bf16x4;
typedef __attribute__((ext_vector_type(4))) float f32x4;

#define XST 328  // x slab row stride (bf16): 656 B = 16B-mult; col banks 2-way
#define HST 40   // h row stride (bf16): 80 B = 16B-mult; col banks 2-way
#define WTS 88   // W row stride (bf16): 176 B = 16B-mult; col banks 2-way

// ---------------------------------------------------------------------------
// Fused encoder (MFMA, coalesced LDS-staged x) + gravity (R6 butterfly-free).
// Block = 256 thr = 4 waves = 64 tokens; wave owns 16 tokens throughout.
//  enc:  slab x[64][300] loaded FLAT-coalesced (float4), cvt bf16 -> LDS
//        (K padded 300->320). h = relu(x@w1+b1) via 10 MFMA (A=x, B=w1 frags);
//        embT = w2T . hT via 1 MFMA -> C-layout == gravity Bp-layout directly.
//  grav: S^T = Aaug.Paug (pn folded in); w=rcp; F^T,F2^T MFMAs; no shuffles.
// launch_bounds(256,1): no VGPR cap (R3: a cap caused 68 MB scratch spill).
// ---------------------------------------------------------------------------
__global__ __launch_bounds__(256, 1)
void k_enc_grav(const float* __restrict__ x, const float* __restrict__ w1,
                const float* __restrict__ b1, const float* __restrict__ w2,
                const float* __restrict__ b2, const float* __restrict__ att,
                float* __restrict__ ws)
{
    __shared__ __align__(16) char smem[64 * XST * 2 + 4 * 16 * HST * 2]; // 47104 B
    __bf16* xs = (__bf16*)smem;                       // 64 x XST
    __bf16* hl = (__bf16*)(smem + 64 * XST * 2);      // 4 waves x 16 x HST
    __bf16* Wl = (__bf16*)smem;                       // gravity phase: aliases xs

    const int tid  = threadIdx.x;
    const int wave = tid >> 6, lane = tid & 63;
    const int quad = lane >> 4, col = lane & 15;
    const int tok0 = blockIdx.x * 64;

    // ---- stage A: flat-coalesced slab load, f32 -> bf16, into padded rows ----
    {
        const f32x4* xg = (const f32x4*)(x + (size_t)tok0 * IND);   // 4800 float4s
        #pragma unroll
        for (int i = 0; i < 19; ++i) {
            const int idx = i * 256 + tid;
            if (idx < 4800) {
                f32x4 v = xg[idx];
                const int row = idx / 75, c4 = idx - row * 75;
                bf16x4 b;
                #pragma unroll
                for (int e = 0; e < 4; ++e) b[e] = (__bf16)v[e];
                *(bf16x4*)(xs + row * XST + c4 * 4) = b;
            }
        }
        if (tid < 64) {       // zero K-pad [300,320)
            #pragma unroll
            for (int c = 0; c < 20; ++c) xs[tid * XST + 300 + c] = (__bf16)0.f;
        }
    }

    // ---- w1 B-frags (10 K-steps), one-time; B[k][n=j=col], k=s*32+quad*8+j ----
    bf16x8 w1f[10];
    #pragma unroll
    for (int s = 0; s < 10; ++s)
        #pragma unroll
        for (int j = 0; j < 8; ++j) {
            const int k = s * 32 + quad * 8 + j;
            w1f[s][j] = (k < IND) ? (__bf16)w1[k * HID + col] : (__bf16)0.f;
        }
    __syncthreads();

    // ---- h = relu(x @ w1 + b1): A-frag rows = this wave's 16 tokens ----
    {
        const float b1c = b1[col];
        f32x4 hacc = {b1c, b1c, b1c, b1c};
        const __bf16* myx = xs + (wave * 16 + col) * XST + quad * 8;
        #pragma unroll
        for (int s = 0; s < 10; ++s) {
            bf16x8 af = *(const bf16x8*)(myx + s * 32);
            hacc = __builtin_amdgcn_mfma_f32_16x16x32_bf16(af, w1f[s], hacc, 0, 0, 0);
        }
        // C-layout: lane holds h[token=quad*4+r][j=col] -> wave-private LDS
        __bf16* myh = hl + wave * 16 * HST;
        #pragma unroll
        for (int r = 0; r < 4; ++r)
            myh[(quad * 4 + r) * HST + col] = (__bf16)fmaxf(hacc[r], 0.f);
    }

    // ---- embT = w2T . hT + b2: C-layout == Bp-layout (token=col, d=quad*4+r) ----
    f32x4 p;
    {
        bf16x8 w2tf;          // A[m=d=col][k=j], j padded 16->32
        #pragma unroll
        for (int j = 0; j < 8; ++j) {
            const int k = quad * 8 + j;
            w2tf[j] = (k < HID) ? (__bf16)w2[k * LAT + col] : (__bf16)0.f;
        }
        bf16x8 bh;            // B[k=j][n=token=col]
        #pragma unroll
        for (int e = 0; e < 8; ++e) bh[e] = (__bf16)0.f;
        if (quad < 2)
            bh = *(const bf16x8*)(hl + wave * 16 * HST + col * HST + quad * 8);
        f32x4 pacc = *(const f32x4*)(b2 + quad * 4);
        p = __builtin_amdgcn_mfma_f32_16x16x32_bf16(w2tf, bh, pacc, 0, 0, 0);
    }
    __syncthreads();   // xs/hl dead; Wl may overwrite

    // ---- gravity constants ----
    const f32x4 zf = {0.f, 0.f, 0.f, 0.f};
    bf16x8 ones8;
    #pragma unroll
    for (int e = 0; e < 8; ++e) ones8[e] = (__bf16)1.0f;

    bf16x8 aS[4];   // A[m=16i+col][k]: k even -> -2*att[m][quad*4+k/2], odd -> 1
    #pragma unroll
    for (int i = 0; i < 4; ++i) {
        f32x4 av = *(const f32x4*)(att + (16 * i + col) * LAT + quad * 4);
        #pragma unroll
        for (int m = 0; m < 4; ++m) {
            aS[i][2 * m]     = (__bf16)(-2.0f * av[m]);
            aS[i][2 * m + 1] = (__bf16)1.0f;
        }
    }
    f32x4 sanv[4];  // |a|^2 at C-layout positions
    {
        float nrm[4];
        #pragma unroll
        for (int i = 0; i < 4; ++i) {
            const float* ar = att + (16 * i + col) * LAT;
            float s = 0.f;
            #pragma unroll
            for (int k = 0; k < LAT; ++k) s = fmaf(ar[k], ar[k], s);
            nrm[i] = s;
        }
        #pragma unroll
        for (int i = 0; i < 4; ++i)
            #pragma unroll
            for (int r = 0; r < 4; ++r)
                sanv[i][r] = __shfl(nrm[i], 16 * quad + quad * 4 + r);
    }
    bf16x8 aF[2];   // A[m=d=col][k=a=32h+quad*8+j]
    #pragma unroll
    for (int h = 0; h < 2; ++h)
        #pragma unroll
        for (int j = 0; j < 8; ++j)
            aF[h][j] = (__bf16)att[(32 * h + quad * 8 + j) * LAT + col];

    __bf16* myW = Wl + wave * 16 * WTS;

    float cd = 0.f;
    #pragma unroll 1
    for (int it = 0; it < NITER; ++it) {
        bf16x8 bp;   // B[k][n=token=col]: k even -> p[dim], odd -> p^2
        #pragma unroll
        for (int m = 0; m < 4; ++m) {
            float v = p[m];
            bp[2 * m]     = (__bf16)v;
            bp[2 * m + 1] = (__bf16)(v * v);
        }
        f32x4 sf[4];
        #pragma unroll
        for (int i = 0; i < 4; ++i)
            sf[i] = __builtin_amdgcn_mfma_f32_16x16x32_bf16(aS[i], bp, zf, 0, 0, 0);

        #pragma unroll
        for (int i = 0; i < 4; ++i) {
            bf16x4 wp;
            #pragma unroll
            for (int r = 0; r < 4; ++r)
                wp[r] = (__bf16)__builtin_amdgcn_rcpf(sf[i][r] + sanv[i][r]);
            *(bf16x4*)(myW + col * WTS + 16 * i + quad * 4) = wp;
        }
        bf16x8 bw0 = *(bf16x8*)(myW + col * WTS + quad * 8);
        bf16x8 bw1 = *(bf16x8*)(myW + col * WTS + 32 + quad * 8);

        f32x4 F  = __builtin_amdgcn_mfma_f32_16x16x32_bf16(aF[0], bw0, zf, 0, 0, 0);
        F  = __builtin_amdgcn_mfma_f32_16x16x32_bf16(aF[1], bw1, F,  0, 0, 0);
        f32x4 F2 = __builtin_amdgcn_mfma_f32_16x16x32_bf16(ones8, bw0, zf, 0, 0, 0);
        F2 = __builtin_amdgcn_mfma_f32_16x16x32_bf16(ones8, bw1, F2, 0, 0, 0);

        const bool last = (it == NITER - 1);
        #pragma unroll
        for (int r = 0; r < 4; ++r) {
            float np = fmaf(p[r], fmaf(F2[r], -0.1f * GRAV, 1.0f),
                            (0.1f * GRAV) * F[r]);
            if (last) { float d = np - p[r]; cd = fmaf(d, d, cd); }
            p[r] = np;
        }
    }

    // ---- reductions ----
    f32x4 fs = p;
    #pragma unroll
    for (int m = 1; m <= 8; m <<= 1)
        #pragma unroll
        for (int r = 0; r < 4; ++r) fs[r] += __shfl_xor(fs[r], m);
    const int b = blockIdx.x >> 5;   // 32 blocks (64 tokens) per batch row
    if (col == 0) {
        #pragma unroll
        for (int r = 0; r < 4; ++r)
            atomicAdd(ws + WS_FIELD + b * LAT + quad * 4 + r, fs[r]);
    }
    float c2 = cd;
    c2 += __shfl_xor(c2, 1);  c2 += __shfl_xor(c2, 2);  c2 += __shfl_xor(c2, 4);
    c2 += __shfl_xor(c2, 8);  c2 += __shfl_xor(c2, 16); c2 += __shfl_xor(c2, 32);
    if (lane == 0) atomicAdd(ws + WS_CHG, c2);
}

// ---------------------------------------------------------------------------
// Kernel 2: fused finalize + broadcast.
// ---------------------------------------------------------------------------
#define CHUNK 8192
#define CPB   (SS * IND / CHUNK)    // 75
__global__ __launch_bounds__(256)
void k_bcast(const float* __restrict__ dw1, const float* __restrict__ db1,
             const float* __restrict__ dw2, const float* __restrict__ db2,
             const float* __restrict__ mw,  const float* __restrict__ mb,
             const float* __restrict__ ws, float* __restrict__ out)
{
    __shared__ float sf[LAT];
    __shared__ float sh[HID];
    __shared__ __align__(16) float srow[IND];
    const int blk = blockIdx.x;
    const int b = blk / CPB, c = blk % CPB;
    const int t = threadIdx.x;

    if (t < LAT) {
        float f = ws[WS_FIELD + b * LAT + t] * (1.f / SS);
        sf[t] = f;
        if (c == 0) out[OFF_FIELD + b * LAT + t] = f;
    }
    __syncthreads();
    if (t < HID) {
        float a = db1[t];
        #pragma unroll
        for (int d = 0; d < LAT; ++d) a = fmaf(sf[d], dw1[d * HID + t], a);
        sh[t] = fmaxf(a, 0.f);
    }
    if (c == 0 && t == 32) {
        float a = mb[0];
        #pragma unroll
        for (int d = 0; d < LAT; ++d) a = fmaf(sf[d], mw[d], a);
        out[OFF_MASS + b] = 1.f / (1.f + expf(-a));
    }
    if (blk == 0 && t == 33) out[OFF_CHG] = sqrtf(ws[WS_CHG]);
    __syncthreads();
    if (t < IND) {
        float a = db2[t];
        #pragma unroll
        for (int j = 0; j < HID; ++j) a = fmaf(sh[j], dw2[j * IND + t], a);
        srow[t] = a;
    }
    if (t < IND - 256) {
        const int tc = t + 256;
        float a2 = db2[tc];
        #pragma unroll
        for (int j = 0; j < HID; ++j) a2 = fmaf(sh[j], dw2[j * IND + tc], a2);
        srow[tc] = a2;
    }
    __syncthreads();
    f32x4* o = (f32x4*)(out + OFF_REC + (size_t)b * (SS * IND) + (size_t)c * CHUNK);
    #pragma unroll
    for (int i = 0; i < CHUNK / 4 / 256; ++i) {
        const int o4 = i * 256 + t;
        const int r  = (c * CHUNK + o4 * 4) % IND;   // r % 4 == 0
        f32x4 v = *(const f32x4*)(srow + r);
        __builtin_nontemporal_store(v, o + o4);
    }
}

extern "C" void kernel_launch(void* const* d_in, const int* in_sizes, int n_in,
                              void* d_out, int out_size, void* d_ws, size_t ws_size,
                              hipStream_t stream)
{
    const float* x   = (const float*)d_in[0];
    const float* ew1 = (const float*)d_in[1];
    const float* eb1 = (const float*)d_in[2];
    const float* ew2 = (const float*)d_in[3];
    const float* eb2 = (const float*)d_in[4];
    const float* att = (const float*)d_in[5];
    const float* dw1 = (const float*)d_in[6];
    const float* db1 = (const float*)d_in[7];
    const float* dw2 = (const float*)d_in[8];
    const float* db2 = (const float*)d_in[9];
    const float* mw  = (const float*)d_in[10];
    const float* mb  = (const float*)d_in[11];
    float* out = (float*)d_out;
    float* ws  = (float*)d_ws;

    (void)hipMemsetAsync(ws, 0, (WS_CHG + 1) * sizeof(float), stream);
    k_enc_grav<<<BB * SS / 64, 256, 0, stream>>>(x, ew1, eb1, ew2, eb2, att, ws);
    k_bcast<<<BB * CPB, 256, 0, stream>>>(dw1, db1, dw2, db2, mw, mb, ws, out);
}

// Round 10
// 223.156 us; speedup vs baseline: 1.1478x; 1.0488x over previous
//
#include <hip/hip_runtime.h>
#include <cmath>

#define BB 32
#define SS 2048
#define IND 300
#define HID 16
#define LAT 16
#define NA 64
#define NITER 20
#define GRAV 0.01f

// d_out layout (floats): field[32*16] | rec[32*2048*300] | masses[32] | change[1]
#define OFF_FIELD 0
#define OFF_REC   512
#define OFF_MASS  (512 + BB*SS*IND)
#define OFF_CHG   (OFF_MASS + BB)

// d_ws layout (floats)
#define WS_FIELD 0      // 512 accumulators
#define WS_CHG   512    // 1 accumulator
// p[65536][16] staging lives in d_out's rec region (overwritten later by bcast)

typedef __attribute__((ext_vector_type(8))) __bf16 bf16x8;
typedef __attribute__((ext_vector_type(4))) __bf16 bf16x4;
typedef __attribute__((ext_vector_type(4))) float f32x4;

#define XST 328  // x slab row stride (bf16): 656 B; row-to-row bank offset 4
#define HST 40   // h row stride (bf16): 80 B
#define WTS 88   // W row stride (bf16): 176 B; <=2-way banks

// ---------------------------------------------------------------------------
// Kernel 1: MFMA encoder (memory-bound phase; 42 KB LDS is fine here).
// Slab x[64][300] loaded flat-coalesced f32x4 -> bf16 LDS (K pad 300->320).
// h = relu(x@w1+b1): 10 MFMA; embT = w2T.hT + b2: 1 MFMA -> C-layout ==
// gravity Bp-layout; p stored to pbuf with zero conversions.
// ---------------------------------------------------------------------------
__global__ __launch_bounds__(256, 1)
void k_enc(const float* __restrict__ x, const float* __restrict__ w1,
           const float* __restrict__ b1, const float* __restrict__ w2,
           const float* __restrict__ b2, float* __restrict__ pbuf)
{
    __shared__ __align__(16) char smem[64 * XST * 2 + 4 * 16 * HST * 2];
    __bf16* xs = (__bf16*)smem;
    __bf16* hl = (__bf16*)(smem + 64 * XST * 2);

    const int tid  = threadIdx.x;
    const int wave = tid >> 6, lane = tid & 63;
    const int quad = lane >> 4, col = lane & 15;
    const int tok0 = blockIdx.x * 64;

    {
        const f32x4* xg = (const f32x4*)(x + (size_t)tok0 * IND);   // 4800 f32x4
        #pragma unroll
        for (int i = 0; i < 19; ++i) {
            const int idx = i * 256 + tid;
            if (idx < 4800) {
                f32x4 v = xg[idx];
                const int row = idx / 75, c4 = idx - row * 75;
                bf16x4 b;
                #pragma unroll
                for (int e = 0; e < 4; ++e) b[e] = (__bf16)v[e];
                *(bf16x4*)(xs + row * XST + c4 * 4) = b;
            }
        }
        if (tid < 64) {
            #pragma unroll
            for (int c = 0; c < 20; ++c) xs[tid * XST + 300 + c] = (__bf16)0.f;
        }
    }

    bf16x8 w1f[10];   // B[k][n=j=col], k=s*32+quad*8+j
    #pragma unroll
    for (int s = 0; s < 10; ++s)
        #pragma unroll
        for (int j = 0; j < 8; ++j) {
            const int k = s * 32 + quad * 8 + j;
            w1f[s][j] = (k < IND) ? (__bf16)w1[k * HID + col] : (__bf16)0.f;
        }
    __syncthreads();

    {
        const float b1c = b1[col];
        f32x4 hacc = {b1c, b1c, b1c, b1c};
        const __bf16* myx = xs + (wave * 16 + col) * XST + quad * 8;
        #pragma unroll
        for (int s = 0; s < 10; ++s) {
            bf16x8 af = *(const bf16x8*)(myx + s * 32);
            hacc = __builtin_amdgcn_mfma_f32_16x16x32_bf16(af, w1f[s], hacc, 0, 0, 0);
        }
        __bf16* myh = hl + wave * 16 * HST;
        #pragma unroll
        for (int r = 0; r < 4; ++r)
            myh[(quad * 4 + r) * HST + col] = (__bf16)fmaxf(hacc[r], 0.f);
    }

    f32x4 p;
    {
        bf16x8 w2tf;   // A[m=d=col][k=j], j padded 16->32
        #pragma unroll
        for (int j = 0; j < 8; ++j) {
            const int k = quad * 8 + j;
            w2tf[j] = (k < HID) ? (__bf16)w2[k * LAT + col] : (__bf16)0.f;
        }
        bf16x8 bh;
        #pragma unroll
        for (int e = 0; e < 8; ++e) bh[e] = (__bf16)0.f;
        if (quad < 2)
            bh = *(const bf16x8*)(hl + wave * 16 * HST + col * HST + quad * 8);
        f32x4 pacc = *(const f32x4*)(b2 + quad * 4);
        p = __builtin_amdgcn_mfma_f32_16x16x32_bf16(w2tf, bh, pacc, 0, 0, 0);
    }
    ((f32x4*)pbuf)[(size_t)(tok0 + wave * 16 + col) * 4 + quad] = p;
}

// ---------------------------------------------------------------------------
// Kernel 2: gravity (latency-bound phase; small LDS, high occupancy).
// R6/R7 transposed butterfly-free math, 2 MFMA tiles per wave (32 tok/wave).
// ---------------------------------------------------------------------------
__global__ __launch_bounds__(256, 1)
void k_grav(const float* __restrict__ att, const float* __restrict__ pbuf,
            float* __restrict__ ws)
{
    __shared__ __bf16 Wl[4][2][16 * WTS];   // 22528 B
    const int tid  = threadIdx.x;
    const int wave = tid >> 6, lane = tid & 63;
    const int quad = lane >> 4, col = lane & 15;

    const f32x4 zf = {0.f, 0.f, 0.f, 0.f};
    bf16x8 ones8;
    #pragma unroll
    for (int e = 0; e < 8; ++e) ones8[e] = (__bf16)1.0f;

    bf16x8 aS[4];   // A[m=16i+col][k]: k even -> -2*att[m][quad*4+k/2], odd -> 1
    #pragma unroll
    for (int i = 0; i < 4; ++i) {
        f32x4 av = *(const f32x4*)(att + (16 * i + col) * LAT + quad * 4);
        #pragma unroll
        for (int m = 0; m < 4; ++m) {
            aS[i][2 * m]     = (__bf16)(-2.0f * av[m]);
            aS[i][2 * m + 1] = (__bf16)1.0f;
        }
    }
    f32x4 sanv[4];  // |a|^2 at C-layout positions
    {
        float nrm[4];
        #pragma unroll
        for (int i = 0; i < 4; ++i) {
            const float* ar = att + (16 * i + col) * LAT;
            float s = 0.f;
            #pragma unroll
            for (int k = 0; k < LAT; ++k) s = fmaf(ar[k], ar[k], s);
            nrm[i] = s;
        }
        #pragma unroll
        for (int i = 0; i < 4; ++i)
            #pragma unroll
            for (int r = 0; r < 4; ++r)
                sanv[i][r] = __shfl(nrm[i], 16 * quad + quad * 4 + r);
    }
    bf16x8 aF[2];   // A[m=d=col][k=a=32h+quad*8+j]
    #pragma unroll
    for (int h = 0; h < 2; ++h)
        #pragma unroll
        for (int j = 0; j < 8; ++j)
            aF[h][j] = (__bf16)att[(32 * h + quad * 8 + j) * LAT + col];

    const int t0 = blockIdx.x * 128 + wave * 32 + col;
    f32x4 p[2];
    p[0] = ((const f32x4*)pbuf)[(size_t)t0 * 4 + quad];
    p[1] = ((const f32x4*)pbuf)[(size_t)(t0 + 16) * 4 + quad];

    __bf16* myW[2] = { &Wl[wave][0][0], &Wl[wave][1][0] };

    float cd = 0.f;
    #pragma unroll 1
    for (int it = 0; it < NITER; ++it) {
        bf16x8 bp[2];
        #pragma unroll
        for (int s = 0; s < 2; ++s)
            #pragma unroll
            for (int m = 0; m < 4; ++m) {
                float v = p[s][m];
                bp[s][2 * m]     = (__bf16)v;
                bp[s][2 * m + 1] = (__bf16)(v * v);
            }
        f32x4 sf[2][4];
        #pragma unroll
        for (int s = 0; s < 2; ++s)
            #pragma unroll
            for (int i = 0; i < 4; ++i)
                sf[s][i] = __builtin_amdgcn_mfma_f32_16x16x32_bf16(aS[i], bp[s], zf, 0, 0, 0);

        #pragma unroll
        for (int s = 0; s < 2; ++s)
            #pragma unroll
            for (int i = 0; i < 4; ++i) {
                bf16x4 wp;
                #pragma unroll
                for (int r = 0; r < 4; ++r)
                    wp[r] = (__bf16)__builtin_amdgcn_rcpf(sf[s][i][r] + sanv[i][r]);
                *(bf16x4*)(myW[s] + col * WTS + 16 * i + quad * 4) = wp;
            }
        bf16x8 bw[2][2];
        #pragma unroll
        for (int s = 0; s < 2; ++s)
            #pragma unroll
            for (int h = 0; h < 2; ++h)
                bw[s][h] = *(bf16x8*)(myW[s] + col * WTS + 32 * h + quad * 8);

        const bool last = (it == NITER - 1);
        #pragma unroll
        for (int s = 0; s < 2; ++s) {
            f32x4 F  = __builtin_amdgcn_mfma_f32_16x16x32_bf16(aF[0], bw[s][0], zf, 0, 0, 0);
            F  = __builtin_amdgcn_mfma_f32_16x16x32_bf16(aF[1], bw[s][1], F,  0, 0, 0);
            f32x4 F2 = __builtin_amdgcn_mfma_f32_16x16x32_bf16(ones8, bw[s][0], zf, 0, 0, 0);
            F2 = __builtin_amdgcn_mfma_f32_16x16x32_bf16(ones8, bw[s][1], F2, 0, 0, 0);
            #pragma unroll
            for (int r = 0; r < 4; ++r) {
                float np = fmaf(p[s][r], fmaf(F2[r], -0.1f * GRAV, 1.0f),
                                (0.1f * GRAV) * F[r]);
                if (last) { float d = np - p[s][r]; cd = fmaf(d, d, cd); }
                p[s][r] = np;
            }
        }
    }

    f32x4 fs;
    #pragma unroll
    for (int r = 0; r < 4; ++r) fs[r] = p[0][r] + p[1][r];
    #pragma unroll
    for (int m = 1; m <= 8; m <<= 1)
        #pragma unroll
        for (int r = 0; r < 4; ++r) fs[r] += __shfl_xor(fs[r], m);
    const int b = blockIdx.x >> 4;   // 16 blocks (128 tokens) per batch row
    if (col == 0) {
        #pragma unroll
        for (int r = 0; r < 4; ++r)
            atomicAdd(ws + WS_FIELD + b * LAT + quad * 4 + r, fs[r]);
    }
    float c2 = cd;
    c2 += __shfl_xor(c2, 1);  c2 += __shfl_xor(c2, 2);  c2 += __shfl_xor(c2, 4);
    c2 += __shfl_xor(c2, 8);  c2 += __shfl_xor(c2, 16); c2 += __shfl_xor(c2, 32);
    if (lane == 0) atomicAdd(ws + WS_CHG, c2);
}

// ---------------------------------------------------------------------------
// Kernel 3: fused finalize + broadcast.
// ---------------------------------------------------------------------------
#define CHUNK 8192
#define CPB   (SS * IND / CHUNK)    // 75
__global__ __launch_bounds__(256)
void k_bcast(const float* __restrict__ dw1, const float* __restrict__ db1,
             const float* __restrict__ dw2, const float* __restrict__ db2,
             const float* __restrict__ mw,  const float* __restrict__ mb,
             const float* __restrict__ ws, float* __restrict__ out)
{
    __shared__ float sf[LAT];
    __shared__ float sh[HID];
    __shared__ __align__(16) float srow[IND];
    const int blk = blockIdx.x;
    const int b = blk / CPB, c = blk % CPB;
    const int t = threadIdx.x;

    if (t < LAT) {
        float f = ws[WS_FIELD + b * LAT + t] * (1.f / SS);
        sf[t] = f;
        if (c == 0) out[OFF_FIELD + b * LAT + t] = f;
    }
    __syncthreads();
    if (t < HID) {
        float a = db1[t];
        #pragma unroll
        for (int d = 0; d < LAT; ++d) a = fmaf(sf[d], dw1[d * HID + t], a);
        sh[t] = fmaxf(a, 0.f);
    }
    if (c == 0 && t == 32) {
        float a = mb[0];
        #pragma unroll
        for (int d = 0; d < LAT; ++d) a = fmaf(sf[d], mw[d], a);
        out[OFF_MASS + b] = 1.f / (1.f + expf(-a));
    }
    if (blk == 0 && t == 33) out[OFF_CHG] = sqrtf(ws[WS_CHG]);
    __syncthreads();
    if (t < IND) {
        float a = db2[t];
        #pragma unroll
        for (int j = 0; j < HID; ++j) a = fmaf(sh[j], dw2[j * IND + t], a);
        srow[t] = a;
    }
    if (t < IND - 256) {
        const int tc = t + 256;
        float a2 = db2[tc];
        #pragma unroll
        for (int j = 0; j < HID; ++j) a2 = fmaf(sh[j], dw2[j * IND + tc], a2);
        srow[tc] = a2;
    }
    __syncthreads();
    f32x4* o = (f32x4*)(out + OFF_REC + (size_t)b * (SS * IND) + (size_t)c * CHUNK);
    #pragma unroll
    for (int i = 0; i < CHUNK / 4 / 256; ++i) {
        const int o4 = i * 256 + t;
        const int r  = (c * CHUNK + o4 * 4) % IND;   // r % 4 == 0
        f32x4 v = *(const f32x4*)(srow + r);
        __builtin_nontemporal_store(v, o + o4);
    }
}

extern "C" void kernel_launch(void* const* d_in, const int* in_sizes, int n_in,
                              void* d_out, int out_size, void* d_ws, size_t ws_size,
                              hipStream_t stream)
{
    const float* x   = (const float*)d_in[0];
    const float* ew1 = (const float*)d_in[1];
    const float* eb1 = (const float*)d_in[2];
    const float* ew2 = (const float*)d_in[3];
    const float* eb2 = (const float*)d_in[4];
    const float* att = (const float*)d_in[5];
    const float* dw1 = (const float*)d_in[6];
    const float* db1 = (const float*)d_in[7];
    const float* dw2 = (const float*)d_in[8];
    const float* db2 = (const float*)d_in[9];
    const float* mw  = (const float*)d_in[10];
    const float* mb  = (const float*)d_in[11];
    float* out = (float*)d_out;
    float* ws  = (float*)d_ws;
    float* pbuf = out + OFF_REC;   // 4 MB p staging in rec region (overwritten by k_bcast)

    (void)hipMemsetAsync(ws, 0, (WS_CHG + 1) * sizeof(float), stream);
    k_enc <<<BB * SS / 64, 256, 0, stream>>>(x, ew1, eb1, ew2, eb2, pbuf);
    k_grav<<<BB * SS / 128, 256, 0, stream>>>(att, pbuf, ws);
    k_bcast<<<BB * CPB, 256, 0, stream>>>(dw1, db1, dw2, db2, mw, mb, ws, out);
}